// Round 6
// baseline (276.238 us; speedup 1.0000x reference)
//
#include <hip/hip_runtime.h>
#include <hip/hip_bf16.h>

#define N_SITES 200000
#define CIN 256
#define CMID 64
#define KVOL 9

using bf16x8 = __attribute__((ext_vector_type(8))) short;
using f32x4  = __attribute__((ext_vector_type(4))) float;

__device__ __forceinline__ short f2bf(float f) {
    union { float f; unsigned u; } v; v.f = f;
    unsigned r = v.u + 0x7fffu + ((v.u >> 16) & 1u);   // RNE
    return (short)(r >> 16);
}

__device__ __forceinline__ f32x4 mfma16(bf16x8 a, bf16x8 b, f32x4 c) {
    return __builtin_amdgcn_mfma_f32_16x16x32_bf16(a, b, c, 0, 0, 0);
}

// ---------------- K0: pre-convert W2,W3 to bf16 transposed (co-major) layouts
__global__ __launch_bounds__(256) void k0_convert(const float* __restrict__ W2,
                                                  const float* __restrict__ W3,
                                                  short* __restrict__ W2T,
                                                  short* __restrict__ W3T) {
    int t = blockIdx.x * 256 + threadIdx.x;
    if (t < KVOL * CMID * CMID) {
        int kk = t >> 12, rem = t & 4095, co = rem >> 6, k = rem & 63;
        W2T[t] = f2bf(W2[kk * 4096 + k * 64 + co]);
    }
    if (t < CMID * CIN) {
        int co = t >> 6, k = t & 63;
        W3T[t] = f2bf(W3[k * 256 + co]);
    }
}

// ---------------- K1: x1 = relu(feat @ W1)  (unchanged — at BW ceiling)
__global__ __launch_bounds__(256) void k1_conv1(const float* __restrict__ feat,
                                                const float* __restrict__ W1,
                                                short* __restrict__ x1) {
    __shared__ short w1t[64][264];   // W1^T
    __shared__ short o1[64][72];     // bf16 out staging
    const int t = threadIdx.x;
    const int lane = t & 63, w = t >> 6;
    const int r = lane & 15, g = lane >> 4;

    #pragma unroll
    for (int q = 0; q < 16; ++q) {
        int k0 = 4 * w + 16 * q;
        float v0 = W1[(k0 + 0) * 64 + lane];
        float v1 = W1[(k0 + 1) * 64 + lane];
        float v2 = W1[(k0 + 2) * 64 + lane];
        float v3 = W1[(k0 + 3) * 64 + lane];
        *(short4*)&w1t[lane][k0] = make_short4(f2bf(v0), f2bf(v1), f2bf(v2), f2bf(v3));
    }
    __syncthreads();

    const int row0 = blockIdx.x * 64 + w * 16;
    const float* ap = feat + (size_t)(row0 + r) * CIN + g * 8;

    f32x4 acc[4] = {};
    #pragma unroll
    for (int ks = 0; ks < 8; ++ks) {
        f32x4 a0 = *(const f32x4*)(ap + ks * 32);
        f32x4 a1 = *(const f32x4*)(ap + ks * 32 + 4);
        bf16x8 af;
        #pragma unroll
        for (int j = 0; j < 4; ++j) { af[j] = f2bf(a0[j]); af[4 + j] = f2bf(a1[j]); }
        #pragma unroll
        for (int ct = 0; ct < 4; ++ct) {
            bf16x8 bf = *(const bf16x8*)&w1t[ct * 16 + r][ks * 32 + g * 8];
            acc[ct] = mfma16(af, bf, acc[ct]);
        }
    }
    #pragma unroll
    for (int ct = 0; ct < 4; ++ct)
        #pragma unroll
        for (int j = 0; j < 4; ++j) {
            float v = acc[ct][j];
            o1[w * 16 + g * 4 + j][ct * 16 + r] = f2bf(v > 0.f ? v : 0.f);
        }
    __syncthreads();
    #pragma unroll
    for (int i = 0; i < 2; ++i) {
        int v = t + 256 * i; int row = v >> 3, c8 = v & 7;
        *(bf16x8*)&x1[(size_t)(blockIdx.x * 64 + row) * CMID + c8 * 8] =
            *(const bf16x8*)&o1[row][c8 * 8];
    }
}

// ---------------- K23: fused conv2+relu+conv3+residual+relu — zero barriers,
// no launch-bounds occupancy cap (round-5 lesson: VGPR 64 forced spills)
__global__ __launch_bounds__(256) void k23_fused(const short* __restrict__ x1,
                                                 const short* __restrict__ W2T,
                                                 const short* __restrict__ W3T,
                                                 const int* __restrict__ nbr,
                                                 const float* __restrict__ feat,
                                                 float* __restrict__ out) {
    __shared__ short o2[4][16][72];   // per-wave x2 tile (9.2 KB)
    __shared__ float ot[4][16][36];   // per-wave out staging chunk (9.2 KB)
    const int t = threadIdx.x;
    const int lane = t & 63, w = t >> 6;
    const int r = lane & 15, g = lane >> 4;

    // bijective XCD swizzle (3125 % 8 = 5)
    const int nwg = gridDim.x;
    const int q = nwg >> 3, rm = nwg & 7;
    const int xcd = blockIdx.x & 7, pos = blockIdx.x >> 3;
    const int bid = (xcd < rm) ? xcd * (q + 1) + pos
                               : rm * (q + 1) + (xcd - rm) * q + pos;

    const int row0 = bid * 64 + w * 16;
    const int site = row0 + r;

    int idx9[9];
    #pragma unroll
    for (int kk = 0; kk < 9; ++kk) idx9[kk] = nbr[site * 9 + kk];

    // ---- conv2: gather pipeline depth 2, B-frags straight from global (L1/L2-hot)
    bf16x8 a0p[2] = {}, a1p[2] = {};
    #pragma unroll
    for (int p = 0; p < 2; ++p) {
        int ii = idx9[p];
        if (ii >= 0) { const short* gp = x1 + (size_t)ii * CMID + g * 8;
                       a0p[p] = *(const bf16x8*)gp; a1p[p] = *(const bf16x8*)(gp + 32); }
    }

    f32x4 acc2[4] = {};
    #pragma unroll
    for (int kk = 0; kk < 9; ++kk) {
        const int cur = kk & 1;
        bf16x8 a0 = a0p[cur], a1 = a1p[cur];
        bf16x8 n0 = {}, n1 = {};
        if (kk + 2 < 9) {
            int ii = idx9[kk + 2];
            if (ii >= 0) { const short* gp = x1 + (size_t)ii * CMID + g * 8;
                           n0 = *(const bf16x8*)gp; n1 = *(const bf16x8*)(gp + 32); }
        }
        a0p[cur] = n0; a1p[cur] = n1;
        const short* bp = W2T + kk * 4096 + r * 64 + g * 8;
        #pragma unroll
        for (int ct = 0; ct < 4; ++ct) {
            bf16x8 b0 = *(const bf16x8*)(bp + ct * 1024);
            bf16x8 b1 = *(const bf16x8*)(bp + ct * 1024 + 32);
            acc2[ct] = mfma16(a0, b0, acc2[ct]);
            acc2[ct] = mfma16(a1, b1, acc2[ct]);
        }
    }

    // ---- wave-private x2 bounce (C-layout -> A-fragments), no barrier
    #pragma unroll
    for (int ct = 0; ct < 4; ++ct)
        #pragma unroll
        for (int j = 0; j < 4; ++j) {
            float v = acc2[ct][j];
            o2[w][g * 4 + j][ct * 16 + r] = f2bf(v > 0.f ? v : 0.f);
        }
    asm volatile("s_waitcnt lgkmcnt(0)" ::: "memory");
    bf16x8 a0 = *(const bf16x8*)&o2[w][r][g * 8];
    bf16x8 a1 = *(const bf16x8*)&o2[w][r][32 + g * 8];

    // ---- conv3: B-frags straight from global W3T (L1/L2-hot)
    f32x4 acc3[16];
    const short* wp = W3T + r * 64 + g * 8;
    #pragma unroll
    for (int ct = 0; ct < 16; ++ct) {
        bf16x8 b0 = *(const bf16x8*)(wp + ct * 1024);
        bf16x8 b1 = *(const bf16x8*)(wp + ct * 1024 + 32);
        f32x4 z = {};
        z = mfma16(a0, b0, z);
        acc3[ct] = mfma16(a1, b1, z);
    }

    // ---- epilogue: 8 chunks of 32 cols, wave-private staging,
    // fully contiguous 128B-per-8-lane loads/stores (round-3 mapping)
    #pragma unroll
    for (int c = 0; c < 8; ++c) {
        #pragma unroll
        for (int ci = 0; ci < 2; ++ci)
            #pragma unroll
            for (int j = 0; j < 4; ++j)
                ot[w][g * 4 + j][ci * 16 + r] = acc3[c * 2 + ci][j];
        asm volatile("s_waitcnt lgkmcnt(0)" ::: "memory");
        #pragma unroll
        for (int i = 0; i < 2; ++i) {
            int v = lane + 64 * i;
            int row = v >> 3, c4 = v & 7;
            size_t o = (size_t)(row0 + row) * CIN + c * 32 + c4 * 4;
            f32x4 f = __builtin_nontemporal_load((const f32x4*)&feat[o]);
            f32x4 s = *(const f32x4*)&ot[w][row][c4 * 4];
            f32x4 res;
            #pragma unroll
            for (int j = 0; j < 4; ++j) { float x = s[j] + f[j]; res[j] = x > 0.f ? x : 0.f; }
            __builtin_nontemporal_store(res, (f32x4*)&out[o]);
        }
    }
}

extern "C" void kernel_launch(void* const* d_in, const int* in_sizes, int n_in,
                              void* d_out, int out_size, void* d_ws, size_t ws_size,
                              hipStream_t stream) {
    const float* feat = (const float*)d_in[0];
    const float* W1   = (const float*)d_in[1];
    const float* W2   = (const float*)d_in[2];
    const float* W3   = (const float*)d_in[3];
    const int*   nbr  = (const int*)d_in[4];

    short* x1  = (short*)d_ws;                          // [N,64] bf16, 25.6 MB
    short* W2T = x1 + (size_t)N_SITES * CMID;           // [9][64][64] bf16
    short* W3T = W2T + KVOL * CMID * CMID;              // [256][64] bf16
    float* out = (float*)d_out;

    const int blocks = N_SITES / 64;                    // 3125
    hipLaunchKernelGGL(k0_convert, dim3(144), dim3(256), 0, stream, W2, W3, W2T, W3T);
    hipLaunchKernelGGL(k1_conv1, dim3(blocks), dim3(256), 0, stream, feat, W1, x1);
    hipLaunchKernelGGL(k23_fused, dim3(blocks), dim3(256), 0, stream,
                       x1, W2T, W3T, nbr, feat, out);
}

// Round 7
// 131.606 us; speedup vs baseline: 2.0990x; 2.0990x over previous
//
#include <hip/hip_runtime.h>
#include <hip/hip_bf16.h>

#define N_SITES 200000
#define CIN 256
#define CMID 64
#define KVOL 9

using bf16x8 = __attribute__((ext_vector_type(8))) short;
using f32x4  = __attribute__((ext_vector_type(4))) float;

__device__ __forceinline__ short f2bf(float f) {
    union { float f; unsigned u; } v; v.f = f;
    unsigned r = v.u + 0x7fffu + ((v.u >> 16) & 1u);   // RNE
    return (short)(r >> 16);
}

__device__ __forceinline__ f32x4 mfma16(bf16x8 a, bf16x8 b, f32x4 c) {
    return __builtin_amdgcn_mfma_f32_16x16x32_bf16(a, b, c, 0, 0, 0);
}

// ---------------- K0: pre-convert W2,W3 to bf16 transposed (co-major) layouts
// W2T[kk][co][k] = bf(W2[kk][k][co]);  W3T[co][k] = bf(W3[k][co])
__global__ __launch_bounds__(256) void k0_convert(const float* __restrict__ W2,
                                                  const float* __restrict__ W3,
                                                  short* __restrict__ W2T,
                                                  short* __restrict__ W3T) {
    int t = blockIdx.x * 256 + threadIdx.x;
    if (t < KVOL * CMID * CMID) {
        int kk = t >> 12, rem = t & 4095, co = rem >> 6, k = rem & 63;
        W2T[t] = f2bf(W2[kk * 4096 + k * 64 + co]);
    }
    if (t < CMID * CIN) {
        int co = t >> 6, k = t & 63;
        W3T[t] = f2bf(W3[k * 256 + co]);
    }
}

// ---------------- K1: x1 = relu(feat @ W1)  (unchanged — at BW ceiling)
__global__ __launch_bounds__(256) void k1_conv1(const float* __restrict__ feat,
                                                const float* __restrict__ W1,
                                                short* __restrict__ x1) {
    __shared__ short w1t[64][264];   // W1^T
    __shared__ short o1[64][72];     // bf16 out staging
    const int t = threadIdx.x;
    const int lane = t & 63, w = t >> 6;
    const int r = lane & 15, g = lane >> 4;

    #pragma unroll
    for (int q = 0; q < 16; ++q) {
        int k0 = 4 * w + 16 * q;
        float v0 = W1[(k0 + 0) * 64 + lane];
        float v1 = W1[(k0 + 1) * 64 + lane];
        float v2 = W1[(k0 + 2) * 64 + lane];
        float v3 = W1[(k0 + 3) * 64 + lane];
        *(short4*)&w1t[lane][k0] = make_short4(f2bf(v0), f2bf(v1), f2bf(v2), f2bf(v3));
    }
    __syncthreads();

    const int row0 = blockIdx.x * 64 + w * 16;
    const float* ap = feat + (size_t)(row0 + r) * CIN + g * 8;

    f32x4 acc[4] = {};
    #pragma unroll
    for (int ks = 0; ks < 8; ++ks) {
        f32x4 a0 = *(const f32x4*)(ap + ks * 32);
        f32x4 a1 = *(const f32x4*)(ap + ks * 32 + 4);
        bf16x8 af;
        #pragma unroll
        for (int j = 0; j < 4; ++j) { af[j] = f2bf(a0[j]); af[4 + j] = f2bf(a1[j]); }
        #pragma unroll
        for (int ct = 0; ct < 4; ++ct) {
            bf16x8 bf = *(const bf16x8*)&w1t[ct * 16 + r][ks * 32 + g * 8];
            acc[ct] = mfma16(af, bf, acc[ct]);
        }
    }
    #pragma unroll
    for (int ct = 0; ct < 4; ++ct)
        #pragma unroll
        for (int j = 0; j < 4; ++j) {
            float v = acc[ct][j];
            o1[w * 16 + g * 4 + j][ct * 16 + r] = f2bf(v > 0.f ? v : 0.f);
        }
    __syncthreads();
    #pragma unroll
    for (int i = 0; i < 2; ++i) {
        int v = t + 256 * i; int row = v >> 3, c8 = v & 7;
        *(bf16x8*)&x1[(size_t)(blockIdx.x * 64 + row) * CMID + c8 * 8] =
            *(const bf16x8*)&o1[row][c8 * 8];
    }
}

// ---------------- K23: round-3 skeleton (LDS-staged B) + bf16 staging,
// split conv3 halves, ot aliased onto w2t, wave-private epilogue
__global__ __launch_bounds__(256) void k23_fused(const short* __restrict__ x1,
                                                 const short* __restrict__ W2T,
                                                 const short* __restrict__ W3T,
                                                 const int* __restrict__ nbr,
                                                 const float* __restrict__ feat,
                                                 float* __restrict__ out) {
    __shared__ short w2t[2][64][72];  // 18 KB; epilogue 'ot' aliases this region
    __shared__ short w3t[128][72];    // 18 KB, one 128-col half of W3T
    __shared__ short o2[4][16][72];   // 9 KB, wave-private x2 bounce
    auto ot = reinterpret_cast<float(*)[16][36]>(&w2t[0][0][0]);  // [4][16][36] f32 = 9 KB

    const int t = threadIdx.x;
    const int lane = t & 63, w = t >> 6;
    const int r = lane & 15, g = lane >> 4;

    // bijective XCD swizzle (3125 % 8 = 5)
    const int nwg = gridDim.x;
    const int q = nwg >> 3, rm = nwg & 7;
    const int xcd = blockIdx.x & 7, pos = blockIdx.x >> 3;
    const int bid = (xcd < rm) ? xcd * (q + 1) + pos
                               : rm * (q + 1) + (xcd - rm) * q + pos;

    const int row0 = bid * 64 + w * 16;
    const int site = row0 + r;

    int idx9[9];
    #pragma unroll
    for (int kk = 0; kk < 9; ++kk) idx9[kk] = nbr[site * 9 + kk];

    // stage w2t[0]: flat-contiguous 4KB-per-instr reads, balanced b128 LDS writes
    {
        const short* src = W2T + t * 8;
        bf16x8 v0 = *(const bf16x8*)(src);
        bf16x8 v1 = *(const bf16x8*)(src + 2048);
        *(bf16x8*)&w2t[0][(t >> 3)][(t & 7) * 8] = v0;
        *(bf16x8*)&w2t[0][(t >> 3) + 32][(t & 7) * 8] = v1;
    }
    // gather pipeline depth 3 (statically indexed)
    bf16x8 ga[3], gb[3];
    #pragma unroll
    for (int p = 0; p < 3; ++p) {
        ga[p] = (bf16x8){}; gb[p] = (bf16x8){};
        int ii = idx9[p];
        if (ii >= 0) { const short* gp = x1 + (size_t)ii * CMID + g * 8;
                       ga[p] = *(const bf16x8*)gp; gb[p] = *(const bf16x8*)(gp + 32); }
    }
    __syncthreads();

    f32x4 acc2[4] = {};
    #pragma unroll
    for (int kk = 0; kk < 9; ++kk) {
        const int cur = kk % 3;
        bf16x8 a0 = ga[cur], a1 = gb[cur];
        bf16x8 n0 = {}, n1 = {};
        if (kk + 3 < 9) {
            int ii = idx9[kk + 3];
            if (ii >= 0) { const short* gp = x1 + (size_t)ii * CMID + g * 8;
                           n0 = *(const bf16x8*)gp; n1 = *(const bf16x8*)(gp + 32); }
        }
        ga[cur] = n0; gb[cur] = n1;
        bf16x8 s0, s1;
        if (kk < 8) {
            const short* src = W2T + (kk + 1) * 4096 + t * 8;
            s0 = *(const bf16x8*)(src);
            s1 = *(const bf16x8*)(src + 2048);
        }
        #pragma unroll
        for (int ct = 0; ct < 4; ++ct) {
            bf16x8 b0 = *(const bf16x8*)&w2t[kk & 1][ct * 16 + r][g * 8];
            bf16x8 b1 = *(const bf16x8*)&w2t[kk & 1][ct * 16 + r][32 + g * 8];
            acc2[ct] = mfma16(a0, b0, acc2[ct]);
            acc2[ct] = mfma16(a1, b1, acc2[ct]);
        }
        if (kk < 8) {
            *(bf16x8*)&w2t[(kk & 1) ^ 1][(t >> 3)][(t & 7) * 8] = s0;
            *(bf16x8*)&w2t[(kk & 1) ^ 1][(t >> 3) + 32][(t & 7) * 8] = s1;
        }
        __syncthreads();
    }

    // x2 bounce: wave-private, lgkmcnt only
    #pragma unroll
    for (int ct = 0; ct < 4; ++ct)
        #pragma unroll
        for (int j = 0; j < 4; ++j) {
            float v = acc2[ct][j];
            o2[w][g * 4 + j][ct * 16 + r] = f2bf(v > 0.f ? v : 0.f);
        }
    asm volatile("s_waitcnt lgkmcnt(0)" ::: "memory");
    bf16x8 A0 = *(const bf16x8*)&o2[w][r][g * 8];
    bf16x8 A1 = *(const bf16x8*)&o2[w][r][32 + g * 8];

    // conv3 + residual + relu in two 128-col halves
    #pragma unroll
    for (int h = 0; h < 2; ++h) {
        __syncthreads();   // h=0: conv2/o2 done; h=1: half-0 w3t reads + epilogue done
        // stage w3t half: 16KB, flat-contiguous 4KB-per-instr reads
        {
            const short* src = W3T + h * 8192 + t * 8;
            #pragma unroll
            for (int i = 0; i < 4; ++i) {
                bf16x8 u = *(const bf16x8*)(src + i * 2048);
                *(bf16x8*)&w3t[(t >> 3) + i * 32][(t & 7) * 8] = u;
            }
        }
        __syncthreads();

        f32x4 acc3[8];
        #pragma unroll
        for (int ct = 0; ct < 8; ++ct) {
            bf16x8 b0 = *(const bf16x8*)&w3t[ct * 16 + r][g * 8];
            bf16x8 b1 = *(const bf16x8*)&w3t[ct * 16 + r][32 + g * 8];
            f32x4 z = {};
            z = mfma16(A0, b0, z);
            acc3[ct] = mfma16(A1, b1, z);
        }

        // epilogue: 4 chunks of 32 cols, wave-private ot (aliases dead w2t)
        #pragma unroll
        for (int c = 0; c < 4; ++c) {
            #pragma unroll
            for (int ci = 0; ci < 2; ++ci)
                #pragma unroll
                for (int j = 0; j < 4; ++j)
                    ot[w][g * 4 + j][ci * 16 + r] = acc3[c * 2 + ci][j];
            asm volatile("s_waitcnt lgkmcnt(0)" ::: "memory");
            #pragma unroll
            for (int i = 0; i < 2; ++i) {
                int v = lane + 64 * i;
                int row = v >> 3, c4 = v & 7;
                size_t o = (size_t)(row0 + row) * CIN + h * 128 + c * 32 + c4 * 4;
                f32x4 f = *(const f32x4*)&feat[o];       // cacheable: harvest L3 from K1
                f32x4 s = *(const f32x4*)&ot[w][row][c4 * 4];
                f32x4 res;
                #pragma unroll
                for (int j = 0; j < 4; ++j) { float x = s[j] + f[j]; res[j] = x > 0.f ? x : 0.f; }
                __builtin_nontemporal_store(res, (f32x4*)&out[o]);
            }
        }
    }
}

extern "C" void kernel_launch(void* const* d_in, const int* in_sizes, int n_in,
                              void* d_out, int out_size, void* d_ws, size_t ws_size,
                              hipStream_t stream) {
    const float* feat = (const float*)d_in[0];
    const float* W1   = (const float*)d_in[1];
    const float* W2   = (const float*)d_in[2];
    const float* W3   = (const float*)d_in[3];
    const int*   nbr  = (const int*)d_in[4];

    short* x1  = (short*)d_ws;                          // [N,64] bf16, 25.6 MB
    short* W2T = x1 + (size_t)N_SITES * CMID;           // [9][64][64] bf16
    short* W3T = W2T + KVOL * CMID * CMID;              // [256][64] bf16
    float* out = (float*)d_out;

    const int blocks = N_SITES / 64;                    // 3125
    hipLaunchKernelGGL(k0_convert, dim3(144), dim3(256), 0, stream, W2, W3, W2T, W3T);
    hipLaunchKernelGGL(k1_conv1, dim3(blocks), dim3(256), 0, stream, feat, W1, x1);
    hipLaunchKernelGGL(k23_fused, dim3(blocks), dim3(256), 0, stream,
                       x1, W2T, W3T, nbr, feat, out);
}

// Round 8
// 120.661 us; speedup vs baseline: 2.2894x; 1.0907x over previous
//
#include <hip/hip_runtime.h>
#include <hip/hip_bf16.h>

#define N_SITES 200000
#define CIN 256
#define CMID 64
#define KVOL 9

using bf16x8 = __attribute__((ext_vector_type(8))) short;
using f32x4  = __attribute__((ext_vector_type(4))) float;

__device__ __forceinline__ short f2bf(float f) {
    union { float f; unsigned u; } v; v.f = f;
    unsigned r = v.u + 0x7fffu + ((v.u >> 16) & 1u);   // RNE
    return (short)(r >> 16);
}

__device__ __forceinline__ f32x4 mfma16(bf16x8 a, bf16x8 b, f32x4 c) {
    return __builtin_amdgcn_mfma_f32_16x16x32_bf16(a, b, c, 0, 0, 0);
}

// ---------------- K1: x1 = relu(feat @ W1)  + folded W2/W3 bf16 transposition
// (K0 folded in: first 144 blocks convert one element/thread — noise vs 34 us)
__global__ __launch_bounds__(256) void k1_conv1(const float* __restrict__ feat,
                                                const float* __restrict__ W1,
                                                const float* __restrict__ W2,
                                                const float* __restrict__ W3,
                                                short* __restrict__ x1,
                                                short* __restrict__ W2T,
                                                short* __restrict__ W3T) {
    const int t = threadIdx.x;
    const int gt = blockIdx.x * 256 + t;
    if (gt < KVOL * CMID * CMID) {            // W2T[kk][co][k] = bf(W2[kk][k][co])
        int kk = gt >> 12, rem = gt & 4095, co = rem >> 6, k = rem & 63;
        W2T[gt] = f2bf(W2[kk * 4096 + k * 64 + co]);
    }
    if (gt < CMID * CIN) {                    // W3T[co][k] = bf(W3[k][co])
        int co = gt >> 6, k = gt & 63;
        W3T[gt] = f2bf(W3[k * 256 + co]);
    }

    __shared__ short w1t[64][264];   // W1^T
    __shared__ short o1[64][72];     // bf16 out staging
    const int lane = t & 63, w = t >> 6;
    const int r = lane & 15, g = lane >> 4;

    #pragma unroll
    for (int qq = 0; qq < 16; ++qq) {
        int k0 = 4 * w + 16 * qq;
        float v0 = W1[(k0 + 0) * 64 + lane];
        float v1 = W1[(k0 + 1) * 64 + lane];
        float v2 = W1[(k0 + 2) * 64 + lane];
        float v3 = W1[(k0 + 3) * 64 + lane];
        *(short4*)&w1t[lane][k0] = make_short4(f2bf(v0), f2bf(v1), f2bf(v2), f2bf(v3));
    }
    __syncthreads();

    const int row0 = blockIdx.x * 64 + w * 16;
    const float* ap = feat + (size_t)(row0 + r) * CIN + g * 8;

    f32x4 acc[4] = {};
    #pragma unroll
    for (int ks = 0; ks < 8; ++ks) {
        f32x4 a0 = *(const f32x4*)(ap + ks * 32);
        f32x4 a1 = *(const f32x4*)(ap + ks * 32 + 4);
        bf16x8 af;
        #pragma unroll
        for (int j = 0; j < 4; ++j) { af[j] = f2bf(a0[j]); af[4 + j] = f2bf(a1[j]); }
        #pragma unroll
        for (int ct = 0; ct < 4; ++ct) {
            bf16x8 bf = *(const bf16x8*)&w1t[ct * 16 + r][ks * 32 + g * 8];
            acc[ct] = mfma16(af, bf, acc[ct]);
        }
    }
    #pragma unroll
    for (int ct = 0; ct < 4; ++ct)
        #pragma unroll
        for (int j = 0; j < 4; ++j) {
            float v = acc[ct][j];
            o1[w * 16 + g * 4 + j][ct * 16 + r] = f2bf(v > 0.f ? v : 0.f);
        }
    __syncthreads();
    #pragma unroll
    for (int i = 0; i < 2; ++i) {
        int v = t + 256 * i; int row = v >> 3, c8 = v & 7;
        *(bf16x8*)&x1[(size_t)(blockIdx.x * 64 + row) * CMID + c8 * 8] =
            *(const bf16x8*)&o1[row][c8 * 8];
    }
}

// ---------------- K23: fused conv2+relu+conv3+residual+relu
// LDS 36 KB (o2 aliases w3t, ot aliases w2t) -> 4 blocks/CU
__global__ __launch_bounds__(256) void k23_fused(const short* __restrict__ x1,
                                                 const short* __restrict__ W2T,
                                                 const short* __restrict__ W3T,
                                                 const int* __restrict__ nbr,
                                                 const float* __restrict__ feat,
                                                 float* __restrict__ out) {
    __shared__ short w2t[2][64][72];  // 18 KB; epilogue 'ot' aliases this region
    __shared__ short w3t[128][72];    // 18 KB; conv2->conv3 'o2' bounce aliases this
    auto ot = reinterpret_cast<float(*)[16][36]>(&w2t[0][0][0]);  // [4][16][36] f32
    auto o2 = reinterpret_cast<short(*)[16][72]>(&w3t[0][0]);     // [4][16][72] bf16

    const int t = threadIdx.x;
    const int lane = t & 63, w = t >> 6;
    const int r = lane & 15, g = lane >> 4;

    // bijective XCD swizzle (3125 % 8 = 5)
    const int nwg = gridDim.x;
    const int q = nwg >> 3, rm = nwg & 7;
    const int xcd = blockIdx.x & 7, pos = blockIdx.x >> 3;
    const int bid = (xcd < rm) ? xcd * (q + 1) + pos
                               : rm * (q + 1) + (xcd - rm) * q + pos;

    const int row0 = bid * 64 + w * 16;
    const int site = row0 + r;

    int idx9[9];
    #pragma unroll
    for (int kk = 0; kk < 9; ++kk) idx9[kk] = nbr[site * 9 + kk];

    // stage w2t[0]: flat-contiguous 4KB-per-instr reads, balanced b128 LDS writes
    {
        const short* src = W2T + t * 8;
        bf16x8 v0 = *(const bf16x8*)(src);
        bf16x8 v1 = *(const bf16x8*)(src + 2048);
        *(bf16x8*)&w2t[0][(t >> 3)][(t & 7) * 8] = v0;
        *(bf16x8*)&w2t[0][(t >> 3) + 32][(t & 7) * 8] = v1;
    }
    // gather pipeline depth 3 (statically indexed)
    bf16x8 ga[3], gb[3];
    #pragma unroll
    for (int p = 0; p < 3; ++p) {
        ga[p] = (bf16x8){}; gb[p] = (bf16x8){};
        int ii = idx9[p];
        if (ii >= 0) { const short* gp = x1 + (size_t)ii * CMID + g * 8;
                       ga[p] = *(const bf16x8*)gp; gb[p] = *(const bf16x8*)(gp + 32); }
    }
    __syncthreads();

    f32x4 acc2[4] = {};
    #pragma unroll
    for (int kk = 0; kk < 9; ++kk) {
        const int cur = kk % 3;
        bf16x8 a0 = ga[cur], a1 = gb[cur];
        bf16x8 n0 = {}, n1 = {};
        if (kk + 3 < 9) {
            int ii = idx9[kk + 3];
            if (ii >= 0) { const short* gp = x1 + (size_t)ii * CMID + g * 8;
                           n0 = *(const bf16x8*)gp; n1 = *(const bf16x8*)(gp + 32); }
        }
        ga[cur] = n0; gb[cur] = n1;
        bf16x8 s0, s1;
        if (kk < 8) {
            const short* src = W2T + (kk + 1) * 4096 + t * 8;
            s0 = *(const bf16x8*)(src);
            s1 = *(const bf16x8*)(src + 2048);
        }
        #pragma unroll
        for (int ct = 0; ct < 4; ++ct) {
            bf16x8 b0 = *(const bf16x8*)&w2t[kk & 1][ct * 16 + r][g * 8];
            bf16x8 b1 = *(const bf16x8*)&w2t[kk & 1][ct * 16 + r][32 + g * 8];
            acc2[ct] = mfma16(a0, b0, acc2[ct]);
            acc2[ct] = mfma16(a1, b1, acc2[ct]);
        }
        if (kk < 8) {
            *(bf16x8*)&w2t[(kk & 1) ^ 1][(t >> 3)][(t & 7) * 8] = s0;
            *(bf16x8*)&w2t[(kk & 1) ^ 1][(t >> 3) + 32][(t & 7) * 8] = s1;
        }
        __syncthreads();
    }

    // x2 bounce: wave-private (o2 aliases w3t — w3t untouched so far; safe)
    #pragma unroll
    for (int ct = 0; ct < 4; ++ct)
        #pragma unroll
        for (int j = 0; j < 4; ++j) {
            float v = acc2[ct][j];
            o2[w][g * 4 + j][ct * 16 + r] = f2bf(v > 0.f ? v : 0.f);
        }
    asm volatile("s_waitcnt lgkmcnt(0)" ::: "memory");
    bf16x8 A0 = *(const bf16x8*)&o2[w][r][g * 8];
    bf16x8 A1 = *(const bf16x8*)&o2[w][r][32 + g * 8];

    // conv3 + residual + relu in two 128-col halves
    #pragma unroll
    for (int h = 0; h < 2; ++h) {
        __syncthreads();   // h=0: all waves have A0/A1 in regs -> o2 region reusable
        // stage w3t half: 16KB, flat-contiguous 4KB-per-instr reads
        {
            const short* src = W3T + h * 8192 + t * 8;
            #pragma unroll
            for (int i = 0; i < 4; ++i) {
                bf16x8 u = *(const bf16x8*)(src + i * 2048);
                *(bf16x8*)&w3t[(t >> 3) + i * 32][(t & 7) * 8] = u;
            }
        }
        __syncthreads();

        f32x4 acc3[8];
        #pragma unroll
        for (int ct = 0; ct < 8; ++ct) {
            bf16x8 b0 = *(const bf16x8*)&w3t[ct * 16 + r][g * 8];
            bf16x8 b1 = *(const bf16x8*)&w3t[ct * 16 + r][32 + g * 8];
            f32x4 z = {};
            z = mfma16(A0, b0, z);
            acc3[ct] = mfma16(A1, b1, z);
        }

        // epilogue: 4 chunks of 32 cols, wave-private ot (aliases dead w2t)
        #pragma unroll
        for (int c = 0; c < 4; ++c) {
            #pragma unroll
            for (int ci = 0; ci < 2; ++ci)
                #pragma unroll
                for (int j = 0; j < 4; ++j)
                    ot[w][g * 4 + j][ci * 16 + r] = acc3[c * 2 + ci][j];
            asm volatile("s_waitcnt lgkmcnt(0)" ::: "memory");
            #pragma unroll
            for (int i = 0; i < 2; ++i) {
                int v = lane + 64 * i;
                int row = v >> 3, c4 = v & 7;
                size_t o = (size_t)(row0 + row) * CIN + h * 128 + c * 32 + c4 * 4;
                f32x4 f = *(const f32x4*)&feat[o];       // cacheable: harvest L3 from K1
                f32x4 s = *(const f32x4*)&ot[w][row][c4 * 4];
                f32x4 res;
                #pragma unroll
                for (int j = 0; j < 4; ++j) { float x = s[j] + f[j]; res[j] = x > 0.f ? x : 0.f; }
                __builtin_nontemporal_store(res, (f32x4*)&out[o]);
            }
        }
    }
}

extern "C" void kernel_launch(void* const* d_in, const int* in_sizes, int n_in,
                              void* d_out, int out_size, void* d_ws, size_t ws_size,
                              hipStream_t stream) {
    const float* feat = (const float*)d_in[0];
    const float* W1   = (const float*)d_in[1];
    const float* W2   = (const float*)d_in[2];
    const float* W3   = (const float*)d_in[3];
    const int*   nbr  = (const int*)d_in[4];

    short* x1  = (short*)d_ws;                          // [N,64] bf16, 25.6 MB
    short* W2T = x1 + (size_t)N_SITES * CMID;           // [9][64][64] bf16
    short* W3T = W2T + KVOL * CMID * CMID;              // [256][64] bf16
    float* out = (float*)d_out;

    const int blocks = N_SITES / 64;                    // 3125
    hipLaunchKernelGGL(k1_conv1, dim3(blocks), dim3(256), 0, stream,
                       feat, W1, W2, W3, x1, W2T, W3T);
    hipLaunchKernelGGL(k23_fused, dim3(blocks), dim3(256), 0, stream,
                       x1, W2T, W3T, nbr, feat, out);
}